// Round 1
// baseline (90.424 us; speedup 1.0000x reference)
//
#include <hip/hip_runtime.h>

namespace {
constexpr int Bn = 8, LQ = 512, LK = 512, Dn = 64;
constexpr int QT = 8, KT = 128, NT = LK / KT;
constexpr float C2 = 2.8853900817779268f; // 2*log2(e)

// score(b,q,k) = sum_d tanh(q_d+k_d) = 64 - 2*sum_d rcp(e^{2q_d} e^{2k_d} + 1)
// p = e^{score-64} = exp2(-C2 * acc)  -> numerically safe (acc in (0,64)),
// identical p used for numerator and denominator so softmax is exact.
__global__ __launch_bounds__(256, 2)
void addattn(const float* __restrict__ Q, const float* __restrict__ K,
             const float* __restrict__ V, float* __restrict__ O)
{
  __shared__ __align__(16) float ek[KT][Dn + 1];   // e^{2k}, pad 65 -> 2-way (free)
  __shared__ __align__(16) float eqs[QT][Dn];      // e^{2q}, uniform b128 reads
  __shared__ __align__(16) float pl[QT][KT + 4];   // p tile, rows 528B (16B mult)
  __shared__ float lsum[QT];

  const int t  = threadIdx.x;
  const int bb = blockIdx.x >> 6;
  const int q0 = (blockIdx.x & 63) * QT;

  // ---- stage eq = exp(2q) for the 8 q-rows (one-time)
  if (t < 128) {
    const int r = t >> 4, d4 = t & 15;
    float4 qv = *(const float4*)(Q + ((bb * LQ + q0 + r) * Dn) + d4 * 4);
    float4 e;
    e.x = __builtin_amdgcn_exp2f(qv.x * C2);
    e.y = __builtin_amdgcn_exp2f(qv.y * C2);
    e.z = __builtin_amdgcn_exp2f(qv.z * C2);
    e.w = __builtin_amdgcn_exp2f(qv.w * C2);
    *(float4*)&eqs[r][d4 * 4] = e;
  }
  if (t < QT) lsum[t] = 0.f;
  __syncthreads();

  float ac0 = 0.f, ac1 = 0.f, ac2 = 0.f, ac3 = 0.f; // PV accumulators (persist)

  const int kk   = t & 127;        // score phase: k within tile
  const int qg   = (t >> 7) * 4;   // score phase: q group base (0 or 4)
  const int rr   = (t >> 4) & 7;   // PV phase: q row
  const int dq   = t & 15;         // PV phase: d quad
  const int half = t >> 7;         // PV phase: k half of tile

  for (int tile = 0; tile < NT; ++tile) {
    const int k0 = tile * KT;

    // ---- stage ek = exp(2k) tile [128][64] (coalesced global, 2-way-free LDS writes)
    #pragma unroll
    for (int pass = 0; pass < 8; ++pass) {
      const int f = t + 256 * pass;
      const int sk = f >> 4, sd = f & 15;
      float4 kv = *(const float4*)(K + ((bb * LK + k0 + sk) * Dn) + sd * 4);
      ek[sk][sd * 4 + 0] = __builtin_amdgcn_exp2f(kv.x * C2);
      ek[sk][sd * 4 + 1] = __builtin_amdgcn_exp2f(kv.y * C2);
      ek[sk][sd * 4 + 2] = __builtin_amdgcn_exp2f(kv.z * C2);
      ek[sk][sd * 4 + 3] = __builtin_amdgcn_exp2f(kv.w * C2);
    }
    __syncthreads();

    // ---- scores: thread owns 4 q-rows x 1 k; inner loop over d.
    //      1 lane-varying b32 (ek) reused across 4 q's; eq is wave-uniform b128.
    {
      float a0 = 0.f, a1 = 0.f, a2 = 0.f, a3 = 0.f;
      #pragma unroll
      for (int d4 = 0; d4 < 16; ++d4) {
        const float4 e0 = *(const float4*)&eqs[qg + 0][d4 * 4];
        const float4 e1 = *(const float4*)&eqs[qg + 1][d4 * 4];
        const float4 e2 = *(const float4*)&eqs[qg + 2][d4 * 4];
        const float4 e3 = *(const float4*)&eqs[qg + 3][d4 * 4];
        const float x0 = ek[kk][d4 * 4 + 0];
        const float x1 = ek[kk][d4 * 4 + 1];
        const float x2 = ek[kk][d4 * 4 + 2];
        const float x3 = ek[kk][d4 * 4 + 3];
        a0 += __builtin_amdgcn_rcpf(fmaf(e0.x, x0, 1.f));
        a1 += __builtin_amdgcn_rcpf(fmaf(e1.x, x0, 1.f));
        a2 += __builtin_amdgcn_rcpf(fmaf(e2.x, x0, 1.f));
        a3 += __builtin_amdgcn_rcpf(fmaf(e3.x, x0, 1.f));
        a0 += __builtin_amdgcn_rcpf(fmaf(e0.y, x1, 1.f));
        a1 += __builtin_amdgcn_rcpf(fmaf(e1.y, x1, 1.f));
        a2 += __builtin_amdgcn_rcpf(fmaf(e2.y, x1, 1.f));
        a3 += __builtin_amdgcn_rcpf(fmaf(e3.y, x1, 1.f));
        a0 += __builtin_amdgcn_rcpf(fmaf(e0.z, x2, 1.f));
        a1 += __builtin_amdgcn_rcpf(fmaf(e1.z, x2, 1.f));
        a2 += __builtin_amdgcn_rcpf(fmaf(e2.z, x2, 1.f));
        a3 += __builtin_amdgcn_rcpf(fmaf(e3.z, x2, 1.f));
        a0 += __builtin_amdgcn_rcpf(fmaf(e0.w, x3, 1.f));
        a1 += __builtin_amdgcn_rcpf(fmaf(e1.w, x3, 1.f));
        a2 += __builtin_amdgcn_rcpf(fmaf(e2.w, x3, 1.f));
        a3 += __builtin_amdgcn_rcpf(fmaf(e3.w, x3, 1.f));
      }
      pl[qg + 0][kk] = __builtin_amdgcn_exp2f(-C2 * a0);
      pl[qg + 1][kk] = __builtin_amdgcn_exp2f(-C2 * a1);
      pl[qg + 2][kk] = __builtin_amdgcn_exp2f(-C2 * a2);
      pl[qg + 3][kk] = __builtin_amdgcn_exp2f(-C2 * a3);
    }
    __syncthreads();

    // ---- row sums of p (denominator), 32 lanes per row, in-wave shuffle reduce
    {
      const int r = t >> 5, c = t & 31;
      float4 p4 = *(const float4*)&pl[r][c * 4];
      float s = (p4.x + p4.y) + (p4.z + p4.w);
      s += __shfl_xor(s, 1);
      s += __shfl_xor(s, 2);
      s += __shfl_xor(s, 4);
      s += __shfl_xor(s, 8);
      s += __shfl_xor(s, 16);
      if (c == 0) lsum[r] += s;   // single writer per row
    }

    // ---- PV accumulate: V straight from global (L1/L2 resident, 128KB/batch)
    {
      const float* vb = V + ((bb * LK + k0 + half * 64) * Dn) + dq * 4;
      const float* prow = &pl[rr][half * 64];
      #pragma unroll 8
      for (int j = 0; j < 64; ++j) {
        float4 v4 = *(const float4*)(vb + j * Dn);
        float pw = prow[j];       // wave-uniform per 16-lane group -> broadcast
        ac0 = fmaf(pw, v4.x, ac0);
        ac1 = fmaf(pw, v4.y, ac1);
        ac2 = fmaf(pw, v4.z, ac2);
        ac3 = fmaf(pw, v4.w, ac3);
      }
    }
    __syncthreads();   // protect ek/pl before next tile's staging
  }

  // ---- epilogue: combine the two k-halves (reuse eqs as scratch), normalize
  if (half == 1) {
    *(float4*)&eqs[rr][dq * 4] = make_float4(ac0, ac1, ac2, ac3);
  }
  __syncthreads();
  if (half == 0) {
    float4 o = *(const float4*)&eqs[rr][dq * 4];
    float inv = 1.0f / lsum[rr];
    float4 r;
    r.x = (ac0 + o.x) * inv;
    r.y = (ac1 + o.y) * inv;
    r.z = (ac2 + o.z) * inv;
    r.w = (ac3 + o.w) * inv;
    *(float4*)(O + ((bb * LQ + q0 + rr) * Dn) + dq * 4) = r;
  }
}
} // namespace

extern "C" void kernel_launch(void* const* d_in, const int* in_sizes, int n_in,
                              void* d_out, int out_size, void* d_ws, size_t ws_size,
                              hipStream_t stream) {
  (void)in_sizes; (void)n_in; (void)d_ws; (void)ws_size; (void)out_size;
  const float* Q = (const float*)d_in[0];
  const float* K = (const float*)d_in[1];
  const float* V = (const float*)d_in[2];
  float* O = (float*)d_out;
  addattn<<<dim3(Bn * (LQ / QT)), dim3(256), 0, stream>>>(Q, K, V, O);
}